// Round 1
// baseline (371.524 us; speedup 1.0000x reference)
//
#include <hip/hip_runtime.h>
#include <stdint.h>

#define TT_ 2048
#define CC_ 1024

typedef unsigned short u16;
typedef __bf16 bf16x8 __attribute__((ext_vector_type(8)));
typedef float f32x4 __attribute__((ext_vector_type(4)));
typedef unsigned short u16x8 __attribute__((ext_vector_type(8)));

__device__ __forceinline__ u16 f2bf(float f) {
  unsigned u = __float_as_uint(f);
  u += 0x7fff + ((u >> 16) & 1);
  return (u16)(u >> 16);
}

__device__ __forceinline__ float gelu_f(float t) {
  float t3 = t * t * t;
  return 0.5f * t * (1.f + tanhf(0.79788456080286536f * (t + 0.044715f * t3)));
}

__device__ __forceinline__ void async_cp16(const u16* g, u16* l) {
  __builtin_amdgcn_global_load_lds(
      (const __attribute__((address_space(1))) void*)(uintptr_t)g,
      (__attribute__((address_space(3))) void*)(uint32_t)(uintptr_t)l,
      16, 0, 0);
}

// ---- transpose + convert: W[K][N] f32 -> WT[N][K] bf16 ----
__global__ __launch_bounds__(256) void kconv_t(const float* __restrict__ W,
                                               u16* __restrict__ WT, int K, int N) {
  __shared__ float t[32][33];
  int n0 = blockIdx.x * 32, k0 = blockIdx.y * 32;
  int tx = threadIdx.x & 31, ty = threadIdx.x >> 5;
#pragma unroll
  for (int r = 0; r < 4; ++r)
    t[ty + 8 * r][tx] = W[(size_t)(k0 + ty + 8 * r) * N + n0 + tx];
  __syncthreads();
#pragma unroll
  for (int r = 0; r < 4; ++r)
    WT[(size_t)(n0 + ty + 8 * r) * K + k0 + tx] = f2bf(t[tx][ty + 8 * r]);
}

// ---- layernorm rows of 1024: f32 in -> bf16 out ----
__global__ __launch_bounds__(256) void kln(const float* __restrict__ x,
                                           const float* __restrict__ g,
                                           const float* __restrict__ b,
                                           u16* __restrict__ out) {
  int row = blockIdx.x, tid = threadIdx.x;
  const float4* xr = (const float4*)(x + (size_t)row * CC_);
  float4 v = xr[tid];
  float s = v.x + v.y + v.z + v.w;
  float s2 = v.x * v.x + v.y * v.y + v.z * v.z + v.w * v.w;
#pragma unroll
  for (int off = 32; off; off >>= 1) { s += __shfl_down(s, off); s2 += __shfl_down(s2, off); }
  __shared__ float rs[4], rq[4];
  int w = tid >> 6;
  if ((tid & 63) == 0) { rs[w] = s; rq[w] = s2; }
  __syncthreads();
  s = rs[0] + rs[1] + rs[2] + rs[3];
  s2 = rq[0] + rq[1] + rq[2] + rq[3];
  float mean = s * (1.f / CC_);
  float var = s2 * (1.f / CC_) - mean * mean;
  float rstd = rsqrtf(var + 1e-5f);
  float4 gv = ((const float4*)g)[tid];
  float4 bv = ((const float4*)b)[tid];
  u16* orow = out + (size_t)row * CC_ + tid * 4;
  orow[0] = f2bf((v.x - mean) * rstd * gv.x + bv.x);
  orow[1] = f2bf((v.y - mean) * rstd * gv.y + bv.y);
  orow[2] = f2bf((v.z - mean) * rstd * gv.z + bv.z);
  orow[3] = f2bf((v.w - mean) * rstd * gv.w + bv.w);
}

// ---- GEMM: C[M,N] = A[M,K](bf16) * BT[N,K]^T(bf16) + bias, epilogue variants ----
// EPI 0: bf16 out = acc+bias ; 1: f32 out = acc+bias+resid ; 2: bf16 out = gelu(acc+bias)
template <int EPI>
__global__ __launch_bounds__(256) void kgemm(const u16* __restrict__ A,
                                             const u16* __restrict__ BTm,
                                             const float* __restrict__ bias,
                                             const float* __restrict__ resid,
                                             void* __restrict__ out, int M, int N, int K) {
  __shared__ __align__(16) u16 As[128 * 32];
  __shared__ __align__(16) u16 Bs[128 * 32];
  const int tid = threadIdx.x, lane = tid & 63, w = tid >> 6;
  const int llo = lane & 15, lhi = lane >> 4;
  const int row0 = blockIdx.y * 128, col0 = blockIdx.x * 128;
  const int wr = w >> 1, wc = w & 1;
  const int crow = lane >> 2;        // row within 16-row chunk
  const int ck = (lane & 3) * 8;     // k-elem offset

  f32x4 acc[4][4] = {};

  for (int k0 = 0; k0 < K; k0 += 32) {
#pragma unroll
    for (int c = w; c < 8; c += 4) {
      int r = c * 16 + crow;
      async_cp16(A + (size_t)(row0 + r) * K + k0 + ck, As + c * 512);
      async_cp16(BTm + (size_t)(col0 + r) * K + k0 + ck, Bs + c * 512);
    }
    asm volatile("s_waitcnt vmcnt(0)" ::: "memory");
    __syncthreads();
    bf16x8 af[4], bfr[4];
#pragma unroll
    for (int m = 0; m < 4; ++m)
      af[m] = *(const bf16x8*)&As[(wr * 64 + m * 16 + llo) * 32 + lhi * 8];
#pragma unroll
    for (int n = 0; n < 4; ++n)
      bfr[n] = *(const bf16x8*)&Bs[(wc * 64 + n * 16 + llo) * 32 + lhi * 8];
#pragma unroll
    for (int m = 0; m < 4; ++m)
#pragma unroll
      for (int n = 0; n < 4; ++n)
        acc[m][n] = __builtin_amdgcn_mfma_f32_16x16x32_bf16(af[m], bfr[n], acc[m][n], 0, 0, 0);
    __syncthreads();
  }

  const int c_row = row0 + wr * 64 + lhi * 4;
  const int c_col = col0 + wc * 64 + llo;
#pragma unroll
  for (int n = 0; n < 4; ++n) {
    int col = c_col + n * 16;
    float bb = bias[col];
#pragma unroll
    for (int m = 0; m < 4; ++m) {
      f32x4 a = acc[m][n];
#pragma unroll
      for (int i = 0; i < 4; ++i) {
        size_t idx = (size_t)(c_row + m * 16 + i) * N + col;
        float val = a[i] + bb;
        if constexpr (EPI == 1) {
          ((float*)out)[idx] = val + resid[idx];
        } else if constexpr (EPI == 2) {
          ((u16*)out)[idx] = f2bf(gelu_f(val));
        } else {
          ((u16*)out)[idx] = f2bf(val);
        }
      }
    }
  }
}

// ---- causal flash attention: qkv bf16 [4096][3072] -> y bf16 [4096][1024] ----
__global__ __launch_bounds__(256) void kattn(const u16* __restrict__ qkv,
                                             u16* __restrict__ y) {
  const int qt = blockIdx.x, h = blockIdx.y, b = blockIdx.z;
  const int tid = threadIdx.x, lane = tid & 63, w = tid >> 6;
  const int llo = lane & 15, lhi = lane >> 4;

  __shared__ __align__(16) u16 Qs[64 * 72];
  __shared__ __align__(16) u16 Ks[64 * 72];
  __shared__ __align__(16) u16 Vt[64 * 72];
  __shared__ __align__(16) u16 Ps[64 * 72];

  const size_t tok0 = (size_t)b * TT_;
  const int q0 = qt * 64;
  const u16* qb = qkv + tok0 * 3072 + h * 64;
  const u16* kb = qb + 1024;
  const u16* vb = qb + 2048;

  const int stk = tid >> 3, sd = (tid & 7) * 8;
#pragma unroll
  for (int it = 0; it < 2; ++it) {
    int tk = it * 32 + stk;
    u16x8 v = *(const u16x8*)(qb + (size_t)(q0 + tk) * 3072 + sd);
    *(u16x8*)(&Qs[tk * 72 + sd]) = v;
  }

  float m_i[4], l_i[4];
  f32x4 o[4] = {};
#pragma unroll
  for (int i = 0; i < 4; ++i) { m_i[i] = -1e30f; l_i[i] = 0.f; }

  for (int j = 0; j <= qt; ++j) {
    __syncthreads();
#pragma unroll
    for (int it = 0; it < 2; ++it) {
      int tk = it * 32 + stk;
      u16x8 kv = *(const u16x8*)(kb + (size_t)(j * 64 + tk) * 3072 + sd);
      *(u16x8*)(&Ks[tk * 72 + sd]) = kv;
      u16x8 vv = *(const u16x8*)(vb + (size_t)(j * 64 + tk) * 3072 + sd);
      int tx = tk ^ sd;  // XOR swizzle: bank-spread scattered V^T writes
#pragma unroll
      for (int e = 0; e < 8; ++e) Vt[(sd + e) * 72 + tx] = vv[e];
    }
    __syncthreads();

    // S = Q K^T (16x16x32 MFMA), wave w owns q-rows [w*16, w*16+16)
    f32x4 s[4] = {};
    bf16x8 aq[2];
#pragma unroll
    for (int kk = 0; kk < 2; ++kk)
      aq[kk] = *(const bf16x8*)&Qs[(w * 16 + llo) * 72 + kk * 32 + lhi * 8];
#pragma unroll
    for (int nb = 0; nb < 4; ++nb) {
#pragma unroll
      for (int kk = 0; kk < 2; ++kk) {
        bf16x8 bk = *(const bf16x8*)&Ks[(nb * 16 + llo) * 72 + kk * 32 + lhi * 8];
        s[nb] = __builtin_amdgcn_mfma_f32_16x16x32_bf16(aq[kk], bk, s[nb], 0, 0, 0);
      }
    }

    // scale + causal mask
    const int colb = j * 64 + llo;
    const int qrow = q0 + w * 16 + lhi * 4;
    float sc[4][4];
#pragma unroll
    for (int nb = 0; nb < 4; ++nb)
#pragma unroll
      for (int i = 0; i < 4; ++i) {
        float v = s[nb][i] * 0.125f;
        if (colb + nb * 16 > qrow + i) v = -1e30f;
        sc[nb][i] = v;
      }

    // wave-parallel online softmax (16-lane groups hold one row)
#pragma unroll
    for (int i = 0; i < 4; ++i) {
      float rm = fmaxf(fmaxf(sc[0][i], sc[1][i]), fmaxf(sc[2][i], sc[3][i]));
#pragma unroll
      for (int off = 1; off < 16; off <<= 1) rm = fmaxf(rm, __shfl_xor(rm, off));
      float mnew = fmaxf(m_i[i], rm);
      float corr = __expf(m_i[i] - mnew);
      float p0 = __expf(sc[0][i] - mnew);
      float p1 = __expf(sc[1][i] - mnew);
      float p2 = __expf(sc[2][i] - mnew);
      float p3 = __expf(sc[3][i] - mnew);
      float rsum = p0 + p1 + p2 + p3;
#pragma unroll
      for (int off = 1; off < 16; off <<= 1) rsum += __shfl_xor(rsum, off);
      l_i[i] = l_i[i] * corr + rsum;
      m_i[i] = mnew;
#pragma unroll
      for (int db = 0; db < 4; ++db) o[db][i] *= corr;
      u16* pr = &Ps[(w * 16 + lhi * 4 + i) * 72 + llo];
      pr[0] = f2bf(p0); pr[16] = f2bf(p1); pr[32] = f2bf(p2); pr[48] = f2bf(p3);
    }

    // O += P V
    bf16x8 pa[2];
#pragma unroll
    for (int kk = 0; kk < 2; ++kk)
      pa[kk] = *(const bf16x8*)&Ps[(w * 16 + llo) * 72 + kk * 32 + lhi * 8];
#pragma unroll
    for (int db = 0; db < 4; ++db) {
      int dd = db * 16 + llo;
#pragma unroll
      for (int kk = 0; kk < 2; ++kk) {
        bf16x8 bv = *(const bf16x8*)&Vt[dd * 72 + ((kk * 32 + lhi * 8) ^ (dd & 56))];
        o[db] = __builtin_amdgcn_mfma_f32_16x16x32_bf16(pa[kk], bv, o[db], 0, 0, 0);
      }
    }
  }

#pragma unroll
  for (int i = 0; i < 4; ++i) {
    float inv = 1.f / l_i[i];
    size_t row = tok0 + q0 + w * 16 + lhi * 4 + i;
#pragma unroll
    for (int db = 0; db < 4; ++db)
      y[row * CC_ + h * 64 + db * 16 + llo] = f2bf(o[db][i] * inv);
  }
}

extern "C" void kernel_launch(void* const* d_in, const int* in_sizes, int n_in,
                              void* d_out, int out_size, void* d_ws, size_t ws_size,
                              hipStream_t stream) {
  (void)in_sizes; (void)n_in; (void)out_size; (void)ws_size;
  const float* x      = (const float*)d_in[0];
  const float* ln1g   = (const float*)d_in[1];
  const float* ln1b   = (const float*)d_in[2];
  const float* W_attn = (const float*)d_in[3];
  const float* b_attn = (const float*)d_in[4];
  const float* W_ap   = (const float*)d_in[5];
  const float* b_ap   = (const float*)d_in[6];
  const float* ln2g   = (const float*)d_in[7];
  const float* ln2b   = (const float*)d_in[8];
  const float* W_fc   = (const float*)d_in[9];
  const float* b_fc   = (const float*)d_in[10];
  const float* W_mp   = (const float*)d_in[11];
  const float* b_mp   = (const float*)d_in[12];

  char* p = (char*)d_ws;
  u16* WTattn = (u16*)p; p += (size_t)3072 * 1024 * 2;
  u16* WTap   = (u16*)p; p += (size_t)1024 * 1024 * 2;
  u16* WTfc   = (u16*)p; p += (size_t)4096 * 1024 * 2;
  u16* WTmp   = (u16*)p; p += (size_t)4096 * 1024 * 2;
  u16* xn     = (u16*)p; p += (size_t)4096 * 1024 * 2;
  u16* qkvb   = (u16*)p; p += (size_t)4096 * 3072 * 2;
  u16* yb     = (u16*)p; p += (size_t)4096 * 1024 * 2;
  float* x1   = (float*)p; p += (size_t)4096 * 1024 * 4;
  u16* h2     = (u16*)p; p += (size_t)4096 * 1024 * 2;
  u16* fcb    = qkvb;  // alias: fc [4096][4096] reuses qkv+y region (both dead by then)

  // weight transposes (f32 -> bf16, [K][N] -> [N][K])
  kconv_t<<<dim3(96, 32), 256, 0, stream>>>(W_attn, WTattn, 1024, 3072);
  kconv_t<<<dim3(32, 32), 256, 0, stream>>>(W_ap, WTap, 1024, 1024);
  kconv_t<<<dim3(128, 32), 256, 0, stream>>>(W_fc, WTfc, 1024, 4096);
  kconv_t<<<dim3(32, 128), 256, 0, stream>>>(W_mp, WTmp, 4096, 1024);

  kln<<<4096, 256, 0, stream>>>(x, ln1g, ln1b, xn);
  kgemm<0><<<dim3(24, 32), 256, 0, stream>>>(xn, WTattn, b_attn, nullptr, qkvb, 4096, 3072, 1024);
  kattn<<<dim3(32, 16, 2), 256, 0, stream>>>(qkvb, yb);
  kgemm<1><<<dim3(8, 32), 256, 0, stream>>>(yb, WTap, b_ap, x, x1, 4096, 1024, 1024);
  kln<<<4096, 256, 0, stream>>>(x1, ln2g, ln2b, h2);
  kgemm<2><<<dim3(32, 32), 256, 0, stream>>>(h2, WTfc, b_fc, nullptr, fcb, 4096, 4096, 1024);
  kgemm<1><<<dim3(8, 32), 256, 0, stream>>>(fcb, WTmp, b_mp, x1, (float*)d_out, 4096, 1024, 4096);
}

// Round 2
// 313.691 us; speedup vs baseline: 1.1844x; 1.1844x over previous
//
#include <hip/hip_runtime.h>
#include <stdint.h>

#define TT_ 2048
#define CC_ 1024

typedef unsigned short u16;
typedef __bf16 bf16x8 __attribute__((ext_vector_type(8)));
typedef float f32x4 __attribute__((ext_vector_type(4)));
typedef unsigned short u16x8 __attribute__((ext_vector_type(8)));

__device__ __forceinline__ u16 f2bf(float f) {
  unsigned u = __float_as_uint(f);
  u += 0x7fff + ((u >> 16) & 1);
  return (u16)(u >> 16);
}

__device__ __forceinline__ float gelu_f(float t) {
  float t3 = t * t * t;
  return 0.5f * t * (1.f + tanhf(0.79788456080286536f * (t + 0.044715f * t3)));
}

__device__ __forceinline__ void async_cp16(const u16* g, u16* l) {
  __builtin_amdgcn_global_load_lds(
      (const __attribute__((address_space(1))) void*)(uintptr_t)g,
      (__attribute__((address_space(3))) void*)(uint32_t)(uintptr_t)l,
      16, 0, 0);
}

__device__ __forceinline__ void blockbar() {
  asm volatile("" ::: "memory");
  __builtin_amdgcn_s_barrier();
  asm volatile("" ::: "memory");
}

// ---- transpose + convert: W[K][N] f32 -> WT[N][K] bf16 ----
__global__ __launch_bounds__(256) void kconv_t(const float* __restrict__ W,
                                               u16* __restrict__ WT, int K, int N) {
  __shared__ float t[32][33];
  int n0 = blockIdx.x * 32, k0 = blockIdx.y * 32;
  int tx = threadIdx.x & 31, ty = threadIdx.x >> 5;
#pragma unroll
  for (int r = 0; r < 4; ++r)
    t[ty + 8 * r][tx] = W[(size_t)(k0 + ty + 8 * r) * N + n0 + tx];
  __syncthreads();
#pragma unroll
  for (int r = 0; r < 4; ++r)
    WT[(size_t)(n0 + ty + 8 * r) * K + k0 + tx] = f2bf(t[tx][ty + 8 * r]);
}

// ---- layernorm rows of 1024: f32 in -> bf16 out ----
__global__ __launch_bounds__(256) void kln(const float* __restrict__ x,
                                           const float* __restrict__ g,
                                           const float* __restrict__ b,
                                           u16* __restrict__ out) {
  int row = blockIdx.x, tid = threadIdx.x;
  const float4* xr = (const float4*)(x + (size_t)row * CC_);
  float4 v = xr[tid];
  float s = v.x + v.y + v.z + v.w;
  float s2 = v.x * v.x + v.y * v.y + v.z * v.z + v.w * v.w;
#pragma unroll
  for (int off = 32; off; off >>= 1) { s += __shfl_down(s, off); s2 += __shfl_down(s2, off); }
  __shared__ float rs[4], rq[4];
  int w = tid >> 6;
  if ((tid & 63) == 0) { rs[w] = s; rq[w] = s2; }
  __syncthreads();
  s = rs[0] + rs[1] + rs[2] + rs[3];
  s2 = rq[0] + rq[1] + rq[2] + rq[3];
  float mean = s * (1.f / CC_);
  float var = s2 * (1.f / CC_) - mean * mean;
  float rstd = rsqrtf(var + 1e-5f);
  float4 gv = ((const float4*)g)[tid];
  float4 bv = ((const float4*)b)[tid];
  u16* orow = out + (size_t)row * CC_ + tid * 4;
  orow[0] = f2bf((v.x - mean) * rstd * gv.x + bv.x);
  orow[1] = f2bf((v.y - mean) * rstd * gv.y + bv.y);
  orow[2] = f2bf((v.z - mean) * rstd * gv.z + bv.z);
  orow[3] = f2bf((v.w - mean) * rstd * gv.w + bv.w);
}

// ---- GEMM: C[M,N] = A[M,K](bf16) * BT[N,K]^T(bf16) + bias, epilogue variants ----
template <int EPI>
__global__ __launch_bounds__(256) void kgemm(const u16* __restrict__ A,
                                             const u16* __restrict__ BTm,
                                             const float* __restrict__ bias,
                                             const float* __restrict__ resid,
                                             void* __restrict__ out, int M, int N, int K) {
  __shared__ __align__(16) u16 As[128 * 32];
  __shared__ __align__(16) u16 Bs[128 * 32];
  const int tid = threadIdx.x, lane = tid & 63, w = tid >> 6;
  const int llo = lane & 15, lhi = lane >> 4;
  const int row0 = blockIdx.y * 128, col0 = blockIdx.x * 128;
  const int wr = w >> 1, wc = w & 1;
  const int crow = lane >> 2;
  const int ck = (lane & 3) * 8;

  f32x4 acc[4][4] = {};

  for (int k0 = 0; k0 < K; k0 += 32) {
#pragma unroll
    for (int c = w; c < 8; c += 4) {
      int r = c * 16 + crow;
      async_cp16(A + (size_t)(row0 + r) * K + k0 + ck, As + c * 512);
      async_cp16(BTm + (size_t)(col0 + r) * K + k0 + ck, Bs + c * 512);
    }
    asm volatile("s_waitcnt vmcnt(0)" ::: "memory");
    __syncthreads();
    bf16x8 af[4], bfr[4];
#pragma unroll
    for (int m = 0; m < 4; ++m)
      af[m] = *(const bf16x8*)&As[(wr * 64 + m * 16 + llo) * 32 + lhi * 8];
#pragma unroll
    for (int n = 0; n < 4; ++n)
      bfr[n] = *(const bf16x8*)&Bs[(wc * 64 + n * 16 + llo) * 32 + lhi * 8];
#pragma unroll
    for (int m = 0; m < 4; ++m)
#pragma unroll
      for (int n = 0; n < 4; ++n)
        acc[m][n] = __builtin_amdgcn_mfma_f32_16x16x32_bf16(af[m], bfr[n], acc[m][n], 0, 0, 0);
    __syncthreads();
  }

  const int c_row = row0 + wr * 64 + lhi * 4;
  const int c_col = col0 + wc * 64 + llo;
#pragma unroll
  for (int n = 0; n < 4; ++n) {
    int col = c_col + n * 16;
    float bb = bias[col];
#pragma unroll
    for (int m = 0; m < 4; ++m) {
      f32x4 a = acc[m][n];
#pragma unroll
      for (int i = 0; i < 4; ++i) {
        size_t idx = (size_t)(c_row + m * 16 + i) * N + col;
        float val = a[i] + bb;
        if constexpr (EPI == 1) {
          ((float*)out)[idx] = val + resid[idx];
        } else if constexpr (EPI == 2) {
          ((u16*)out)[idx] = f2bf(gelu_f(val));
        } else {
          ((u16*)out)[idx] = f2bf(val);
        }
      }
    }
  }
}

// ---- V transpose: qkv[.][2048+h*64+d] -> VT[bh][d][T] bf16 ----
__global__ __launch_bounds__(256) void kvtrans(const u16* __restrict__ qkv,
                                               u16* __restrict__ VT) {
  int tt = blockIdx.x;          // token tile of 64
  int bh = blockIdx.y;          // b*16+h
  int b = bh >> 4, h = bh & 15;
  __shared__ u16 t[64][72];
  int r = threadIdx.x >> 3, c0 = (threadIdx.x & 7) * 8;
  const u16* src = qkv + (size_t)(b * TT_ + tt * 64) * 3072 + 2048 + h * 64;
#pragma unroll
  for (int it = 0; it < 2; ++it) {
    int rr = r + it * 32;
    *(u16x8*)&t[rr][c0] = *(const u16x8*)(src + (size_t)rr * 3072 + c0);
  }
  __syncthreads();
  u16* dst = VT + ((size_t)bh * 64) * TT_ + tt * 64;
#pragma unroll
  for (int it = 0; it < 2; ++it) {
    int d = r + it * 32;
    u16x8 v;
#pragma unroll
    for (int e = 0; e < 8; ++e) v[e] = t[c0 + e][d];
    *(u16x8*)(dst + (size_t)d * TT_ + c0) = v;
  }
}

// ---- causal flash attention: QBLK=128, 8 waves, dbuf K/V, swizzled LDS ----
__global__ __launch_bounds__(512, 4) void kattn(const u16* __restrict__ qkv,
                                                const u16* __restrict__ VT,
                                                u16* __restrict__ y) {
  const int h = blockIdx.x, b = blockIdx.y;
  const int qt = 15 - blockIdx.z;            // longest-first dispatch
  const int tid = threadIdx.x, lane = tid & 63, w = tid >> 6;
  const int llo = lane & 15, lhi = lane >> 4;

  __shared__ __align__(16) u16 Qs[128 * 64];
  __shared__ __align__(16) u16 Ks[2][64 * 64];
  __shared__ __align__(16) u16 Vs[2][64 * 64];
  __shared__ __align__(16) u16 Ps[128 * 72];

  const size_t tok0 = (size_t)b * TT_;
  const int q0 = qt * 128;
  const u16* qb = qkv + tok0 * 3072 + h * 64;
  const u16* kb = qb + 1024;

  // stage Q, swizzled rows
  {
    int r8 = tid >> 3, ce = (tid & 7) * 8;
#pragma unroll
    for (int it = 0; it < 2; ++it) {
      int tk = it * 64 + r8;
      u16x8 v = *(const u16x8*)(qb + (size_t)(q0 + tk) * 3072 + ce);
      *(u16x8*)&Qs[tk * 64 + (ce ^ ((tk & 7) << 3))] = v;
    }
  }
  asm volatile("s_waitcnt lgkmcnt(0)" ::: "memory");

  // per-lane pre-swizzled global staging addresses (linear LDS dest)
  const int srow = lane >> 3;
  const int scol = ((lane & 7) * 8) ^ ((srow & 7) << 3);
  const u16* kg = kb + (size_t)(w * 8 + srow) * 3072 + scol;
  const u16* vg = VT + ((size_t)(b * 16 + h) * 64 + w * 8 + srow) * TT_ + scol;

  const int ntiles = 2 * qt + 2;
  async_cp16(kg, &Ks[0][w * 512]);
  async_cp16(vg, &Vs[0][w * 512]);

  blockbar();  // Q visible to all waves

  bf16x8 aq[2];
#pragma unroll
  for (int kk = 0; kk < 2; ++kk)
    aq[kk] = *(const bf16x8*)&Qs[(w * 16 + llo) * 64 + ((kk * 32 + lhi * 8) ^ ((llo & 7) << 3))];

  float m_i[4], l_i[4];
  f32x4 o[4] = {};
#pragma unroll
  for (int i = 0; i < 4; ++i) { m_i[i] = -1e30f; l_i[i] = 0.f; }

  const int row_min = q0 + w * 16, row_max = row_min + 15;
  int buf = 0;

  for (int j = 0; j < ntiles; ++j) {
    if (j + 1 < ntiles) {
      async_cp16(kg + (size_t)(j + 1) * (64 * 3072), &Ks[buf ^ 1][w * 512]);
      async_cp16(vg + (size_t)(j + 1) * 64, &Vs[buf ^ 1][w * 512]);
      asm volatile("s_waitcnt vmcnt(2)" ::: "memory");
    } else {
      asm volatile("s_waitcnt vmcnt(0)" ::: "memory");
    }
    blockbar();  // tile j staged for all waves

    const int kmin = j * 64;
    if (kmin <= row_max) {  // wave not fully above diagonal
      // S = Q K^T
      f32x4 s[4] = {};
#pragma unroll
      for (int nb = 0; nb < 4; ++nb)
#pragma unroll
        for (int kk = 0; kk < 2; ++kk) {
          bf16x8 bk = *(const bf16x8*)&Ks[buf][(nb * 16 + llo) * 64 +
                                              ((kk * 32 + lhi * 8) ^ ((llo & 7) << 3))];
          s[nb] = __builtin_amdgcn_mfma_f32_16x16x32_bf16(aq[kk], bk, s[nb], 0, 0, 0);
        }

      const bool part = (kmin + 63 > row_min);
      float sc[4][4];
#pragma unroll
      for (int nb = 0; nb < 4; ++nb)
#pragma unroll
        for (int i = 0; i < 4; ++i) {
          float v = s[nb][i] * 0.125f;
          if (part && (kmin + nb * 16 + llo > row_min + lhi * 4 + i)) v = -1e30f;
          sc[nb][i] = v;
        }

#pragma unroll
      for (int i = 0; i < 4; ++i) {
        float rm = fmaxf(fmaxf(sc[0][i], sc[1][i]), fmaxf(sc[2][i], sc[3][i]));
#pragma unroll
        for (int off = 1; off < 16; off <<= 1) rm = fmaxf(rm, __shfl_xor(rm, off));
        float mnew = fmaxf(m_i[i], rm);
        float corr = __expf(m_i[i] - mnew);
        float p0 = __expf(sc[0][i] - mnew);
        float p1 = __expf(sc[1][i] - mnew);
        float p2 = __expf(sc[2][i] - mnew);
        float p3 = __expf(sc[3][i] - mnew);
        float rsum = p0 + p1 + p2 + p3;
#pragma unroll
        for (int off = 1; off < 16; off <<= 1) rsum += __shfl_xor(rsum, off);
        l_i[i] = l_i[i] * corr + rsum;
        m_i[i] = mnew;
#pragma unroll
        for (int db = 0; db < 4; ++db) o[db][i] *= corr;
        u16* pr = &Ps[(w * 16 + lhi * 4 + i) * 72 + llo];
        pr[0] = f2bf(p0); pr[16] = f2bf(p1); pr[32] = f2bf(p2); pr[48] = f2bf(p3);
      }

      // O += P V
      bf16x8 pa[2];
#pragma unroll
      for (int kk = 0; kk < 2; ++kk)
        pa[kk] = *(const bf16x8*)&Ps[(w * 16 + llo) * 72 + kk * 32 + lhi * 8];
#pragma unroll
      for (int db = 0; db < 4; ++db)
#pragma unroll
        for (int kk = 0; kk < 2; ++kk) {
          bf16x8 bv = *(const bf16x8*)&Vs[buf][(db * 16 + llo) * 64 +
                                              ((kk * 32 + lhi * 8) ^ ((llo & 7) << 3))];
          o[db] = __builtin_amdgcn_mfma_f32_16x16x32_bf16(pa[kk], bv, o[db], 0, 0, 0);
        }
    }
    blockbar();  // all waves done reading buf before it is re-staged
    buf ^= 1;
  }

#pragma unroll
  for (int i = 0; i < 4; ++i) {
    float inv = 1.f / l_i[i];
    size_t row = tok0 + q0 + w * 16 + lhi * 4 + i;
#pragma unroll
    for (int db = 0; db < 4; ++db)
      y[row * CC_ + h * 64 + db * 16 + llo] = f2bf(o[db][i] * inv);
  }
}

extern "C" void kernel_launch(void* const* d_in, const int* in_sizes, int n_in,
                              void* d_out, int out_size, void* d_ws, size_t ws_size,
                              hipStream_t stream) {
  (void)in_sizes; (void)n_in; (void)out_size; (void)ws_size;
  const float* x      = (const float*)d_in[0];
  const float* ln1g   = (const float*)d_in[1];
  const float* ln1b   = (const float*)d_in[2];
  const float* W_attn = (const float*)d_in[3];
  const float* b_attn = (const float*)d_in[4];
  const float* W_ap   = (const float*)d_in[5];
  const float* b_ap   = (const float*)d_in[6];
  const float* ln2g   = (const float*)d_in[7];
  const float* ln2b   = (const float*)d_in[8];
  const float* W_fc   = (const float*)d_in[9];
  const float* b_fc   = (const float*)d_in[10];
  const float* W_mp   = (const float*)d_in[11];
  const float* b_mp   = (const float*)d_in[12];

  char* p = (char*)d_ws;
  u16* WTattn = (u16*)p; p += (size_t)3072 * 1024 * 2;
  u16* WTap   = (u16*)p; p += (size_t)1024 * 1024 * 2;
  u16* WTfc   = (u16*)p; p += (size_t)4096 * 1024 * 2;
  u16* WTmp   = (u16*)p; p += (size_t)4096 * 1024 * 2;
  u16* xn     = (u16*)p; p += (size_t)4096 * 1024 * 2;
  u16* qkvb   = (u16*)p; p += (size_t)4096 * 3072 * 2;
  u16* yb     = (u16*)p; p += (size_t)4096 * 1024 * 2;
  float* x1   = (float*)p; p += (size_t)4096 * 1024 * 4;
  u16* h2     = (u16*)p; p += (size_t)4096 * 1024 * 2;
  u16* fcb    = qkvb;          // fc activations alias qkv (dead by then)
  u16* VT     = (u16*)x1;      // VT [32][64][2048] aliases x1 (x1 written after attn)

  kconv_t<<<dim3(96, 32), 256, 0, stream>>>(W_attn, WTattn, 1024, 3072);
  kconv_t<<<dim3(32, 32), 256, 0, stream>>>(W_ap, WTap, 1024, 1024);
  kconv_t<<<dim3(128, 32), 256, 0, stream>>>(W_fc, WTfc, 1024, 4096);
  kconv_t<<<dim3(32, 128), 256, 0, stream>>>(W_mp, WTmp, 4096, 1024);

  kln<<<4096, 256, 0, stream>>>(x, ln1g, ln1b, xn);
  kgemm<0><<<dim3(24, 32), 256, 0, stream>>>(xn, WTattn, b_attn, nullptr, qkvb, 4096, 3072, 1024);
  kvtrans<<<dim3(32, 32), 256, 0, stream>>>(qkvb, VT);
  kattn<<<dim3(16, 2, 16), 512, 0, stream>>>(qkvb, VT, yb);
  kgemm<1><<<dim3(8, 32), 256, 0, stream>>>(yb, WTap, b_ap, x, x1, 4096, 1024, 1024);
  kln<<<4096, 256, 0, stream>>>(x1, ln2g, ln2b, h2);
  kgemm<2><<<dim3(32, 32), 256, 0, stream>>>(h2, WTfc, b_fc, nullptr, fcb, 4096, 4096, 1024);
  kgemm<1><<<dim3(8, 32), 256, 0, stream>>>(fcb, WTmp, b_mp, x1, (float*)d_out, 4096, 1024, 4096);
}

// Round 3
// 283.487 us; speedup vs baseline: 1.3106x; 1.1065x over previous
//
#include <hip/hip_runtime.h>
#include <stdint.h>

#define TT_ 2048
#define CC_ 1024

typedef unsigned short u16;
typedef __bf16 bf16x8 __attribute__((ext_vector_type(8)));
typedef float f32x4 __attribute__((ext_vector_type(4)));
typedef unsigned short u16x8 __attribute__((ext_vector_type(8)));

__device__ __forceinline__ u16 f2bf(float f) {
  unsigned u = __float_as_uint(f);
  u += 0x7fff + ((u >> 16) & 1);
  return (u16)(u >> 16);
}

__device__ __forceinline__ float gelu_f(float t) {
  // 0.5t(1+tanh(c(t+0.044715t^3))) == t * sigmoid(2c(t+0.044715t^3))
  float u = 1.5957691216057308f * (t + 0.044715f * t * t * t);
  return t / (1.f + __expf(-u));
}

__device__ __forceinline__ void async_cp16(const u16* g, u16* l) {
  __builtin_amdgcn_global_load_lds(
      (const __attribute__((address_space(1))) void*)(uintptr_t)g,
      (__attribute__((address_space(3))) void*)(uint32_t)(uintptr_t)l,
      16, 0, 0);
}

__device__ __forceinline__ void blockbar() {
  asm volatile("" ::: "memory");
  __builtin_amdgcn_s_barrier();
  asm volatile("" ::: "memory");
}

// ---- transpose + convert: W[K][N] f32 -> WT[N][K] bf16 ----
__global__ __launch_bounds__(256) void kconv_t(const float* __restrict__ W,
                                               u16* __restrict__ WT, int K, int N) {
  __shared__ float t[32][33];
  int n0 = blockIdx.x * 32, k0 = blockIdx.y * 32;
  int tx = threadIdx.x & 31, ty = threadIdx.x >> 5;
#pragma unroll
  for (int r = 0; r < 4; ++r)
    t[ty + 8 * r][tx] = W[(size_t)(k0 + ty + 8 * r) * N + n0 + tx];
  __syncthreads();
#pragma unroll
  for (int r = 0; r < 4; ++r)
    WT[(size_t)(n0 + ty + 8 * r) * K + k0 + tx] = f2bf(t[tx][ty + 8 * r]);
}

// ---- layernorm rows of 1024: f32 in -> bf16 out ----
__global__ __launch_bounds__(256) void kln(const float* __restrict__ x,
                                           const float* __restrict__ g,
                                           const float* __restrict__ b,
                                           u16* __restrict__ out) {
  int row = blockIdx.x, tid = threadIdx.x;
  const float4* xr = (const float4*)(x + (size_t)row * CC_);
  float4 v = xr[tid];
  float s = v.x + v.y + v.z + v.w;
  float s2 = v.x * v.x + v.y * v.y + v.z * v.z + v.w * v.w;
#pragma unroll
  for (int off = 32; off; off >>= 1) { s += __shfl_down(s, off); s2 += __shfl_down(s2, off); }
  __shared__ float rs[4], rq[4];
  int w = tid >> 6;
  if ((tid & 63) == 0) { rs[w] = s; rq[w] = s2; }
  __syncthreads();
  s = rs[0] + rs[1] + rs[2] + rs[3];
  s2 = rq[0] + rq[1] + rq[2] + rq[3];
  float mean = s * (1.f / CC_);
  float var = s2 * (1.f / CC_) - mean * mean;
  float rstd = rsqrtf(var + 1e-5f);
  float4 gv = ((const float4*)g)[tid];
  float4 bv = ((const float4*)b)[tid];
  u16* orow = out + (size_t)row * CC_ + tid * 4;
  orow[0] = f2bf((v.x - mean) * rstd * gv.x + bv.x);
  orow[1] = f2bf((v.y - mean) * rstd * gv.y + bv.y);
  orow[2] = f2bf((v.z - mean) * rstd * gv.z + bv.z);
  orow[3] = f2bf((v.w - mean) * rstd * gv.w + bv.w);
}

// ---- GEMM: C[M,N] = A[M,K] * BT[N,K]^T + bias; dbuf single-barrier K-loop ----
// EPI 0: bf16 out=acc+bias ; 1: f32 out=acc+bias+resid ; 2: bf16 out=gelu(acc+bias)
// NSPLIT=2: blockIdx.z=0 -> normal epilogue over K/2; z=1 -> raw f32 partial.
template <int EPI, int NSPLIT>
__global__ __launch_bounds__(256) void kgemm(const u16* __restrict__ A,
                                             const u16* __restrict__ BTm,
                                             const float* __restrict__ bias,
                                             const float* __restrict__ resid,
                                             void* __restrict__ out,
                                             float* __restrict__ part,
                                             int M, int N, int Ktot) {
  __shared__ __align__(16) u16 As[2][128 * 32];
  __shared__ __align__(16) u16 Bs[2][128 * 32];
  const int tid = threadIdx.x, lane = tid & 63, w = tid >> 6;
  const int llo = lane & 15, lhi = lane >> 4;
  const int row0 = blockIdx.y * 128, col0 = blockIdx.x * 128;
  const int wr = w >> 1, wc = w & 1;
  const int crow = lane >> 2;
  const int ck = (lane & 3) * 8;
  const int Kc = Ktot / NSPLIT;
  const int klo = (NSPLIT > 1) ? blockIdx.z * Kc : 0;

  f32x4 acc[4][4] = {};

  auto stage = [&](int bufi, int kof) {
#pragma unroll
    for (int c = w; c < 8; c += 4) {
      int r = c * 16 + crow;
      async_cp16(A + (size_t)(row0 + r) * Ktot + klo + kof + ck, &As[bufi][c * 512]);
      async_cp16(BTm + (size_t)(col0 + r) * Ktot + klo + kof + ck, &Bs[bufi][c * 512]);
    }
  };

  const int nt = Kc / 32;
  stage(0, 0);
  asm volatile("s_waitcnt vmcnt(0)" ::: "memory");
  blockbar();
  int cur = 0;

  for (int t = 0; t < nt; ++t) {
    if (t + 1 < nt) stage(cur ^ 1, (t + 1) * 32);
    bf16x8 af[4], bfr[4];
#pragma unroll
    for (int m = 0; m < 4; ++m)
      af[m] = *(const bf16x8*)&As[cur][(wr * 64 + m * 16 + llo) * 32 + lhi * 8];
#pragma unroll
    for (int n = 0; n < 4; ++n)
      bfr[n] = *(const bf16x8*)&Bs[cur][(wc * 64 + n * 16 + llo) * 32 + lhi * 8];
#pragma unroll
    for (int m = 0; m < 4; ++m)
#pragma unroll
      for (int n = 0; n < 4; ++n)
        acc[m][n] = __builtin_amdgcn_mfma_f32_16x16x32_bf16(af[m], bfr[n], acc[m][n], 0, 0, 0);
    if (t + 1 < nt) {
      asm volatile("s_waitcnt vmcnt(0)" ::: "memory");
      blockbar();
    }
    cur ^= 1;
  }

  const int c_row = row0 + wr * 64 + lhi * 4;
  const int c_col = col0 + wc * 64 + llo;
  const bool fin = (NSPLIT == 1) || (blockIdx.z == 0);
#pragma unroll
  for (int n = 0; n < 4; ++n) {
    int col = c_col + n * 16;
    float bb = bias[col];
#pragma unroll
    for (int m = 0; m < 4; ++m) {
      f32x4 a = acc[m][n];
#pragma unroll
      for (int i = 0; i < 4; ++i) {
        size_t idx = (size_t)(c_row + m * 16 + i) * N + col;
        if (!fin) {
          part[idx] = a[i];
        } else {
          float val = a[i] + bb;
          if constexpr (EPI == 1) {
            ((float*)out)[idx] = val + resid[idx];
          } else if constexpr (EPI == 2) {
            ((u16*)out)[idx] = f2bf(gelu_f(val));
          } else {
            ((u16*)out)[idx] = f2bf(val);
          }
        }
      }
    }
  }
}

// ---- out[i] += part[i] (f32, vectorized) ----
__global__ __launch_bounds__(256) void kadd(float* __restrict__ out,
                                            const float* __restrict__ part) {
  size_t i = ((size_t)blockIdx.x * 256 + threadIdx.x) * 4;
  float4 o = *(float4*)(out + i);
  float4 p = *(const float4*)(part + i);
  o.x += p.x; o.y += p.y; o.z += p.z; o.w += p.w;
  *(float4*)(out + i) = o;
}

// ---- V transpose: qkv[.][2048+h*64+d] -> VT[bh][d][T] bf16 ----
__global__ __launch_bounds__(256) void kvtrans(const u16* __restrict__ qkv,
                                               u16* __restrict__ VT) {
  int tt = blockIdx.x;
  int bh = blockIdx.y;
  int b = bh >> 4, h = bh & 15;
  __shared__ u16 t[64][72];
  int r = threadIdx.x >> 3, c0 = (threadIdx.x & 7) * 8;
  const u16* src = qkv + (size_t)(b * TT_ + tt * 64) * 3072 + 2048 + h * 64;
#pragma unroll
  for (int it = 0; it < 2; ++it) {
    int rr = r + it * 32;
    *(u16x8*)&t[rr][c0] = *(const u16x8*)(src + (size_t)rr * 3072 + c0);
  }
  __syncthreads();
  u16* dst = VT + ((size_t)bh * 64) * TT_ + tt * 64;
#pragma unroll
  for (int it = 0; it < 2; ++it) {
    int d = r + it * 32;
    u16x8 v;
#pragma unroll
    for (int e = 0; e < 8; ++e) v[e] = t[c0 + e][d];
    *(u16x8*)(dst + (size_t)d * TT_ + c0) = v;
  }
}

// ---- causal flash attention: QBLK=128, 8 waves, dbuf K/V, swizzled LDS ----
__global__ __launch_bounds__(512, 4) void kattn(const u16* __restrict__ qkv,
                                                const u16* __restrict__ VT,
                                                u16* __restrict__ y) {
  const int h = blockIdx.x, b = blockIdx.y;
  const int qt = 15 - blockIdx.z;
  const int tid = threadIdx.x, lane = tid & 63, w = tid >> 6;
  const int llo = lane & 15, lhi = lane >> 4;

  __shared__ __align__(16) u16 Qs[128 * 64];
  __shared__ __align__(16) u16 Ks[2][64 * 64];
  __shared__ __align__(16) u16 Vs[2][64 * 64];
  __shared__ __align__(16) u16 Ps[128 * 72];

  const size_t tok0 = (size_t)b * TT_;
  const int q0 = qt * 128;
  const u16* qb = qkv + tok0 * 3072 + h * 64;
  const u16* kb = qb + 1024;

  {
    int r8 = tid >> 3, ce = (tid & 7) * 8;
#pragma unroll
    for (int it = 0; it < 2; ++it) {
      int tk = it * 64 + r8;
      u16x8 v = *(const u16x8*)(qb + (size_t)(q0 + tk) * 3072 + ce);
      *(u16x8*)&Qs[tk * 64 + (ce ^ ((tk & 7) << 3))] = v;
    }
  }
  asm volatile("s_waitcnt lgkmcnt(0)" ::: "memory");

  const int srow = lane >> 3;
  const int scol = ((lane & 7) * 8) ^ ((srow & 7) << 3);
  const u16* kg = kb + (size_t)(w * 8 + srow) * 3072 + scol;
  const u16* vg = VT + ((size_t)(b * 16 + h) * 64 + w * 8 + srow) * TT_ + scol;

  const int ntiles = 2 * qt + 2;
  async_cp16(kg, &Ks[0][w * 512]);
  async_cp16(vg, &Vs[0][w * 512]);

  blockbar();

  bf16x8 aq[2];
#pragma unroll
  for (int kk = 0; kk < 2; ++kk)
    aq[kk] = *(const bf16x8*)&Qs[(w * 16 + llo) * 64 + ((kk * 32 + lhi * 8) ^ ((llo & 7) << 3))];

  float m_i[4], l_i[4];
  f32x4 o[4] = {};
#pragma unroll
  for (int i = 0; i < 4; ++i) { m_i[i] = -1e30f; l_i[i] = 0.f; }

  const int row_min = q0 + w * 16, row_max = row_min + 15;
  int buf = 0;

  for (int j = 0; j < ntiles; ++j) {
    if (j + 1 < ntiles) {
      async_cp16(kg + (size_t)(j + 1) * (64 * 3072), &Ks[buf ^ 1][w * 512]);
      async_cp16(vg + (size_t)(j + 1) * 64, &Vs[buf ^ 1][w * 512]);
      asm volatile("s_waitcnt vmcnt(2)" ::: "memory");
    } else {
      asm volatile("s_waitcnt vmcnt(0)" ::: "memory");
    }
    blockbar();

    const int kmin = j * 64;
    if (kmin <= row_max) {
      f32x4 s[4] = {};
#pragma unroll
      for (int nb = 0; nb < 4; ++nb)
#pragma unroll
        for (int kk = 0; kk < 2; ++kk) {
          bf16x8 bk = *(const bf16x8*)&Ks[buf][(nb * 16 + llo) * 64 +
                                              ((kk * 32 + lhi * 8) ^ ((llo & 7) << 3))];
          s[nb] = __builtin_amdgcn_mfma_f32_16x16x32_bf16(aq[kk], bk, s[nb], 0, 0, 0);
        }

      const bool part = (kmin + 63 > row_min);
      float sc[4][4];
#pragma unroll
      for (int nb = 0; nb < 4; ++nb)
#pragma unroll
        for (int i = 0; i < 4; ++i) {
          float v = s[nb][i] * 0.125f;
          if (part && (kmin + nb * 16 + llo > row_min + lhi * 4 + i)) v = -1e30f;
          sc[nb][i] = v;
        }

#pragma unroll
      for (int i = 0; i < 4; ++i) {
        float rm = fmaxf(fmaxf(sc[0][i], sc[1][i]), fmaxf(sc[2][i], sc[3][i]));
#pragma unroll
        for (int off = 1; off < 16; off <<= 1) rm = fmaxf(rm, __shfl_xor(rm, off));
        float mnew = fmaxf(m_i[i], rm);
        float corr = __expf(m_i[i] - mnew);
        float p0 = __expf(sc[0][i] - mnew);
        float p1 = __expf(sc[1][i] - mnew);
        float p2 = __expf(sc[2][i] - mnew);
        float p3 = __expf(sc[3][i] - mnew);
        float rsum = p0 + p1 + p2 + p3;
#pragma unroll
        for (int off = 1; off < 16; off <<= 1) rsum += __shfl_xor(rsum, off);
        l_i[i] = l_i[i] * corr + rsum;
        m_i[i] = mnew;
#pragma unroll
        for (int db = 0; db < 4; ++db) o[db][i] *= corr;
        u16* pr = &Ps[(w * 16 + lhi * 4 + i) * 72 + llo];
        pr[0] = f2bf(p0); pr[16] = f2bf(p1); pr[32] = f2bf(p2); pr[48] = f2bf(p3);
      }

      bf16x8 pa[2];
#pragma unroll
      for (int kk = 0; kk < 2; ++kk)
        pa[kk] = *(const bf16x8*)&Ps[(w * 16 + llo) * 72 + kk * 32 + lhi * 8];
#pragma unroll
      for (int db = 0; db < 4; ++db)
#pragma unroll
        for (int kk = 0; kk < 2; ++kk) {
          bf16x8 bv = *(const bf16x8*)&Vs[buf][(db * 16 + llo) * 64 +
                                              ((kk * 32 + lhi * 8) ^ ((llo & 7) << 3))];
          o[db] = __builtin_amdgcn_mfma_f32_16x16x32_bf16(pa[kk], bv, o[db], 0, 0, 0);
        }
    }
    blockbar();
    buf ^= 1;
  }

#pragma unroll
  for (int i = 0; i < 4; ++i) {
    float inv = 1.f / l_i[i];
    size_t row = tok0 + q0 + w * 16 + lhi * 4 + i;
#pragma unroll
    for (int db = 0; db < 4; ++db)
      y[row * CC_ + h * 64 + db * 16 + llo] = f2bf(o[db][i] * inv);
  }
}

extern "C" void kernel_launch(void* const* d_in, const int* in_sizes, int n_in,
                              void* d_out, int out_size, void* d_ws, size_t ws_size,
                              hipStream_t stream) {
  (void)in_sizes; (void)n_in; (void)out_size; (void)ws_size;
  const float* x      = (const float*)d_in[0];
  const float* ln1g   = (const float*)d_in[1];
  const float* ln1b   = (const float*)d_in[2];
  const float* W_attn = (const float*)d_in[3];
  const float* b_attn = (const float*)d_in[4];
  const float* W_ap   = (const float*)d_in[5];
  const float* b_ap   = (const float*)d_in[6];
  const float* ln2g   = (const float*)d_in[7];
  const float* ln2b   = (const float*)d_in[8];
  const float* W_fc   = (const float*)d_in[9];
  const float* b_fc   = (const float*)d_in[10];
  const float* W_mp   = (const float*)d_in[11];
  const float* b_mp   = (const float*)d_in[12];

  char* p = (char*)d_ws;
  u16* WTattn = (u16*)p; p += (size_t)3072 * 1024 * 2;
  u16* WTap   = (u16*)p; p += (size_t)1024 * 1024 * 2;
  u16* WTfc   = (u16*)p; p += (size_t)4096 * 1024 * 2;
  u16* WTmp   = (u16*)p; p += (size_t)4096 * 1024 * 2;
  u16* xn     = (u16*)p; p += (size_t)4096 * 1024 * 2;
  u16* qkvb   = (u16*)p; p += (size_t)4096 * 3072 * 2;
  u16* yb     = (u16*)p; p += (size_t)4096 * 1024 * 2;
  float* x1   = (float*)p; p += (size_t)4096 * 1024 * 4;
  u16* h2     = (u16*)p; p += (size_t)4096 * 1024 * 2;
  u16* fcb    = qkvb;            // fc activations alias qkv+yb (dead by then; sizes match)
  u16* VT     = (u16*)x1;        // VT aliases x1 (x1 written after attn)
  float* mppart = (float*)d_ws;  // 16.78MB over WTattn+WTap+WTfc (all dead at mp time)

  kconv_t<<<dim3(96, 32), 256, 0, stream>>>(W_attn, WTattn, 1024, 3072);
  kconv_t<<<dim3(32, 32), 256, 0, stream>>>(W_ap, WTap, 1024, 1024);
  kconv_t<<<dim3(128, 32), 256, 0, stream>>>(W_fc, WTfc, 1024, 4096);
  kconv_t<<<dim3(32, 128), 256, 0, stream>>>(W_mp, WTmp, 4096, 1024);

  kln<<<4096, 256, 0, stream>>>(x, ln1g, ln1b, xn);
  kgemm<0, 1><<<dim3(24, 32), 256, 0, stream>>>(xn, WTattn, b_attn, nullptr, qkvb, nullptr, 4096, 3072, 1024);
  kvtrans<<<dim3(32, 32), 256, 0, stream>>>(qkvb, VT);
  kattn<<<dim3(16, 2, 16), 512, 0, stream>>>(qkvb, VT, yb);
  kgemm<1, 1><<<dim3(8, 32), 256, 0, stream>>>(yb, WTap, b_ap, x, x1, nullptr, 4096, 1024, 1024);
  kln<<<4096, 256, 0, stream>>>(x1, ln2g, ln2b, h2);
  kgemm<2, 1><<<dim3(32, 32), 256, 0, stream>>>(h2, WTfc, b_fc, nullptr, fcb, nullptr, 4096, 4096, 1024);
  kgemm<1, 2><<<dim3(8, 32, 2), 256, 0, stream>>>(fcb, WTmp, b_mp, x1, (float*)d_out, mppart, 4096, 1024, 4096);
  kadd<<<4096, 256, 0, stream>>>((float*)d_out, mppart);
}

// Round 4
// 279.386 us; speedup vs baseline: 1.3298x; 1.0147x over previous
//
#include <hip/hip_runtime.h>
#include <stdint.h>

#define TT_ 2048
#define CC_ 1024

typedef unsigned short u16;
typedef __bf16 bf16x8 __attribute__((ext_vector_type(8)));
typedef float f32x4 __attribute__((ext_vector_type(4)));
typedef unsigned short u16x8 __attribute__((ext_vector_type(8)));
typedef unsigned int u32x2 __attribute__((ext_vector_type(2)));

__device__ __forceinline__ u16 f2bf(float f) {
  unsigned u = __float_as_uint(f);
  u += 0x7fff + ((u >> 16) & 1);
  return (u16)(u >> 16);
}
__device__ __forceinline__ float bf2f(u16 v) {
  return __uint_as_float(((unsigned)v) << 16);
}

__device__ __forceinline__ float gelu_f(float t) {
  float u = 1.5957691216057308f * (t + 0.044715f * t * t * t);
  return t / (1.f + __expf(-u));
}

__device__ __forceinline__ void async_cp16(const u16* g, u16* l) {
  __builtin_amdgcn_global_load_lds(
      (const __attribute__((address_space(1))) void*)(uintptr_t)g,
      (__attribute__((address_space(3))) void*)(uint32_t)(uintptr_t)l,
      16, 0, 0);
}

__device__ __forceinline__ void blockbar() {
  asm volatile("" ::: "memory");
  __builtin_amdgcn_s_barrier();
  asm volatile("" ::: "memory");
}

// ---- transpose + convert: W[K][N] f32 -> WT[N][K] bf16 ----
__global__ __launch_bounds__(256) void kconv_t(const float* __restrict__ W,
                                               u16* __restrict__ WT, int K, int N) {
  __shared__ float t[32][33];
  int n0 = blockIdx.x * 32, k0 = blockIdx.y * 32;
  int tx = threadIdx.x & 31, ty = threadIdx.x >> 5;
#pragma unroll
  for (int r = 0; r < 4; ++r)
    t[ty + 8 * r][tx] = W[(size_t)(k0 + ty + 8 * r) * N + n0 + tx];
  __syncthreads();
#pragma unroll
  for (int r = 0; r < 4; ++r)
    WT[(size_t)(n0 + ty + 8 * r) * K + k0 + tx] = f2bf(t[tx][ty + 8 * r]);
}

// ---- layernorm rows of 1024: f32 in -> bf16 out ----
__global__ __launch_bounds__(256) void kln(const float* __restrict__ x,
                                           const float* __restrict__ g,
                                           const float* __restrict__ b,
                                           u16* __restrict__ out) {
  int row = blockIdx.x, tid = threadIdx.x;
  const float4* xr = (const float4*)(x + (size_t)row * CC_);
  float4 v = xr[tid];
  float s = v.x + v.y + v.z + v.w;
  float s2 = v.x * v.x + v.y * v.y + v.z * v.z + v.w * v.w;
#pragma unroll
  for (int off = 32; off; off >>= 1) { s += __shfl_down(s, off); s2 += __shfl_down(s2, off); }
  __shared__ float rs[4], rq[4];
  int w = tid >> 6;
  if ((tid & 63) == 0) { rs[w] = s; rq[w] = s2; }
  __syncthreads();
  s = rs[0] + rs[1] + rs[2] + rs[3];
  s2 = rq[0] + rq[1] + rq[2] + rq[3];
  float mean = s * (1.f / CC_);
  float var = s2 * (1.f / CC_) - mean * mean;
  float rstd = rsqrtf(var + 1e-5f);
  float4 gv = ((const float4*)g)[tid];
  float4 bv = ((const float4*)b)[tid];
  u16* orow = out + (size_t)row * CC_ + tid * 4;
  orow[0] = f2bf((v.x - mean) * rstd * gv.x + bv.x);
  orow[1] = f2bf((v.y - mean) * rstd * gv.y + bv.y);
  orow[2] = f2bf((v.z - mean) * rstd * gv.z + bv.z);
  orow[3] = f2bf((v.w - mean) * rstd * gv.w + bv.w);
}

// ---- GEMM: C[M,N] = A[M,K] * BT[N,K]^T + bias; dbuf single-barrier K-loop ----
template <int EPI, int NSPLIT>
__global__ __launch_bounds__(256) void kgemm(const u16* __restrict__ A,
                                             const u16* __restrict__ BTm,
                                             const float* __restrict__ bias,
                                             const float* __restrict__ resid,
                                             void* __restrict__ out,
                                             float* __restrict__ part,
                                             int M, int N, int Ktot) {
  __shared__ __align__(16) u16 As[2][128 * 32];
  __shared__ __align__(16) u16 Bs[2][128 * 32];
  const int tid = threadIdx.x, lane = tid & 63, w = tid >> 6;
  const int llo = lane & 15, lhi = lane >> 4;
  const int row0 = blockIdx.y * 128, col0 = blockIdx.x * 128;
  const int wr = w >> 1, wc = w & 1;
  const int crow = lane >> 2;
  const int ck = (lane & 3) * 8;
  const int Kc = Ktot / NSPLIT;
  const int klo = (NSPLIT > 1) ? blockIdx.z * Kc : 0;

  f32x4 acc[4][4] = {};

  auto stage = [&](int bufi, int kof) {
#pragma unroll
    for (int c = w; c < 8; c += 4) {
      int r = c * 16 + crow;
      async_cp16(A + (size_t)(row0 + r) * Ktot + klo + kof + ck, &As[bufi][c * 512]);
      async_cp16(BTm + (size_t)(col0 + r) * Ktot + klo + kof + ck, &Bs[bufi][c * 512]);
    }
  };

  const int nt = Kc / 32;
  stage(0, 0);
  asm volatile("s_waitcnt vmcnt(0)" ::: "memory");
  blockbar();
  int cur = 0;

  for (int t = 0; t < nt; ++t) {
    if (t + 1 < nt) stage(cur ^ 1, (t + 1) * 32);
    bf16x8 af[4], bfr[4];
#pragma unroll
    for (int m = 0; m < 4; ++m)
      af[m] = *(const bf16x8*)&As[cur][(wr * 64 + m * 16 + llo) * 32 + lhi * 8];
#pragma unroll
    for (int n = 0; n < 4; ++n)
      bfr[n] = *(const bf16x8*)&Bs[cur][(wc * 64 + n * 16 + llo) * 32 + lhi * 8];
#pragma unroll
    for (int m = 0; m < 4; ++m)
#pragma unroll
      for (int n = 0; n < 4; ++n)
        acc[m][n] = __builtin_amdgcn_mfma_f32_16x16x32_bf16(af[m], bfr[n], acc[m][n], 0, 0, 0);
    if (t + 1 < nt) {
      asm volatile("s_waitcnt vmcnt(0)" ::: "memory");
      blockbar();
    }
    cur ^= 1;
  }

  const int c_row = row0 + wr * 64 + lhi * 4;
  const int c_col = col0 + wc * 64 + llo;
  const bool fin = (NSPLIT == 1) || (blockIdx.z == 0);
#pragma unroll
  for (int n = 0; n < 4; ++n) {
    int col = c_col + n * 16;
    float bb = bias[col];
#pragma unroll
    for (int m = 0; m < 4; ++m) {
      f32x4 a = acc[m][n];
#pragma unroll
      for (int i = 0; i < 4; ++i) {
        size_t idx = (size_t)(c_row + m * 16 + i) * N + col;
        if (!fin) {
          part[idx] = a[i];
        } else {
          float val = a[i] + bb;
          if constexpr (EPI == 1) {
            ((float*)out)[idx] = val + resid[idx];
          } else if constexpr (EPI == 2) {
            ((u16*)out)[idx] = f2bf(gelu_f(val));
          } else {
            ((u16*)out)[idx] = f2bf(val);
          }
        }
      }
    }
  }
}

// ---- out[i] += part[i] (f32, vectorized) ----
__global__ __launch_bounds__(256) void kadd(float* __restrict__ out,
                                            const float* __restrict__ part) {
  size_t i = ((size_t)blockIdx.x * 256 + threadIdx.x) * 4;
  float4 o = *(float4*)(out + i);
  float4 p = *(const float4*)(part + i);
  o.x += p.x; o.y += p.y; o.z += p.z; o.w += p.w;
  *(float4*)(out + i) = o;
}

// ---- V transpose: qkv[.][2048+h*64+d] -> VT[bh][d][T] bf16 ----
__global__ __launch_bounds__(256) void kvtrans(const u16* __restrict__ qkv,
                                               u16* __restrict__ VT) {
  int tt = blockIdx.x;
  int bh = blockIdx.y;
  int b = bh >> 4, h = bh & 15;
  __shared__ u16 t[64][72];
  int r = threadIdx.x >> 3, c0 = (threadIdx.x & 7) * 8;
  const u16* src = qkv + (size_t)(b * TT_ + tt * 64) * 3072 + 2048 + h * 64;
#pragma unroll
  for (int it = 0; it < 2; ++it) {
    int rr = r + it * 32;
    *(u16x8*)&t[rr][c0] = *(const u16x8*)(src + (size_t)rr * 3072 + c0);
  }
  __syncthreads();
  u16* dst = VT + ((size_t)bh * 64) * TT_ + tt * 64;
#pragma unroll
  for (int it = 0; it < 2; ++it) {
    int d = r + it * 32;
    u16x8 v;
#pragma unroll
    for (int e = 0; e < 8; ++e) v[e] = t[c0 + e][d];
    *(u16x8*)(dst + (size_t)d * TT_ + c0) = v;
  }
}

// ---- causal flash attention: QBLK=128, 8 waves, dbuf K/V, K-row-permuted LDS,
//      exp2-domain softmax with defer-max, balanced qt pairing ----
__global__ __launch_bounds__(512, 4) void kattn(const u16* __restrict__ qkv,
                                                const u16* __restrict__ VT,
                                                u16* __restrict__ y) {
  const int h = blockIdx.x, b = blockIdx.y;
  const int z = blockIdx.z;
  const int qt = (z < 8) ? (15 - z) : (z - 8);  // CU-pair balanced: 34 tiles/CU
  const int tid = threadIdx.x, lane = tid & 63, w = tid >> 6;
  const int llo = lane & 15, lhi = lane >> 4;

  __shared__ __align__(16) u16 Qs[128 * 64];
  __shared__ __align__(16) u16 Ks[2][64 * 64];
  __shared__ __align__(16) u16 Vs[2][64 * 64];
  __shared__ __align__(16) u16 Ps[128 * 72];

  const size_t tok0 = (size_t)b * TT_;
  const int q0 = qt * 128;
  const u16* qb = qkv + tok0 * 3072 + h * 64;
  const u16* kb = qb + 1024;

  // stage Q, swizzled rows, pre-scaled by 0.125*log2(e) (exp2-domain softmax)
  {
    const float alpha = 0.18033688011112042f;
    int r8 = tid >> 3, ce = (tid & 7) * 8;
#pragma unroll
    for (int it = 0; it < 2; ++it) {
      int tk = it * 64 + r8;
      u16x8 v = *(const u16x8*)(qb + (size_t)(q0 + tk) * 3072 + ce);
#pragma unroll
      for (int e = 0; e < 8; ++e) v[e] = f2bf(bf2f(v[e]) * alpha);
      *(u16x8*)&Qs[tk * 64 + (ce ^ ((tk & 7) << 3))] = v;
    }
  }
  asm volatile("s_waitcnt lgkmcnt(0)" ::: "memory");

  // staging addresses: LDS row position p_; K rows permuted so that
  // S column (nb,llo) = llo*4+nb (k-contiguous per thread)
  const int p_ = w * 8 + (lane >> 3);
  const int krow = ((p_ & 15) << 2) | (p_ >> 4);  // inverse perm
  const int scol = ((lane & 7) * 8) ^ ((p_ & 7) << 3);
  const u16* kg = kb + (size_t)krow * 3072 + scol;
  const u16* vg = VT + ((size_t)(b * 16 + h) * 64 + p_) * TT_ + scol;

  const int ntiles = 2 * qt + 2;
  async_cp16(kg, &Ks[0][w * 512]);
  async_cp16(vg, &Vs[0][w * 512]);

  blockbar();  // Q visible to all waves

  bf16x8 aq[2];
#pragma unroll
  for (int kk = 0; kk < 2; ++kk)
    aq[kk] = *(const bf16x8*)&Qs[(w * 16 + llo) * 64 + ((kk * 32 + lhi * 8) ^ ((llo & 7) << 3))];

  float m_i[4], l_i[4];
  f32x4 o[4] = {};
#pragma unroll
  for (int i = 0; i < 4; ++i) { m_i[i] = -1e30f; l_i[i] = 0.f; }

  const int row_min = q0 + w * 16, row_max = row_min + 15;
  int buf = 0;

  for (int j = 0; j < ntiles; ++j) {
    if (j + 1 < ntiles) {
      async_cp16(kg + (size_t)(j + 1) * (64 * 3072), &Ks[buf ^ 1][w * 512]);
      async_cp16(vg + (size_t)(j + 1) * 64, &Vs[buf ^ 1][w * 512]);
      asm volatile("s_waitcnt vmcnt(2)" ::: "memory");
    } else {
      asm volatile("s_waitcnt vmcnt(0)" ::: "memory");
    }
    blockbar();

    const int kmin = j * 64;
    if (kmin <= row_max) {
      // S' = (alpha*Q) K^T  (exp2 domain)
      f32x4 s[4] = {};
      __builtin_amdgcn_s_setprio(1);
#pragma unroll
      for (int nb = 0; nb < 4; ++nb)
#pragma unroll
        for (int kk = 0; kk < 2; ++kk) {
          bf16x8 bk = *(const bf16x8*)&Ks[buf][(nb * 16 + llo) * 64 +
                                              ((kk * 32 + lhi * 8) ^ ((llo & 7) << 3))];
          s[nb] = __builtin_amdgcn_mfma_f32_16x16x32_bf16(aq[kk], bk, s[nb], 0, 0, 0);
        }
      __builtin_amdgcn_s_setprio(0);

      const bool part = (kmin + 63 > row_min);
      float sc[4][4];
#pragma unroll
      for (int nb = 0; nb < 4; ++nb)
#pragma unroll
        for (int i = 0; i < 4; ++i) {
          float v = s[nb][i];
          // permuted S: column k = kmin + llo*4 + nb
          if (part && (kmin + llo * 4 + nb > row_min + lhi * 4 + i)) v = -1e30f;
          sc[nb][i] = v;
        }

      // row maxes (16-lane groups)
      float rm[4];
#pragma unroll
      for (int i = 0; i < 4; ++i) {
        float r = fmaxf(fmaxf(sc[0][i], sc[1][i]), fmaxf(sc[2][i], sc[3][i]));
#pragma unroll
        for (int off = 1; off < 16; off <<= 1) r = fmaxf(r, __shfl_xor(r, off));
        rm[i] = r;
      }

      // defer-max: rescale only when any row max grew past THR (log2 units)
      bool need = (rm[0] > m_i[0] + 8.f) | (rm[1] > m_i[1] + 8.f) |
                  (rm[2] > m_i[2] + 8.f) | (rm[3] > m_i[3] + 8.f);
      if (__any(need)) {
#pragma unroll
        for (int i = 0; i < 4; ++i) {
          float mn = fmaxf(m_i[i], rm[i]);
          float corr = exp2f(m_i[i] - mn);
          l_i[i] *= corr;
#pragma unroll
          for (int db = 0; db < 4; ++db) o[db][i] *= corr;
          m_i[i] = mn;
        }
      }

#pragma unroll
      for (int i = 0; i < 4; ++i) {
        float p0 = exp2f(sc[0][i] - m_i[i]);
        float p1 = exp2f(sc[1][i] - m_i[i]);
        float p2 = exp2f(sc[2][i] - m_i[i]);
        float p3 = exp2f(sc[3][i] - m_i[i]);
        float rsum = (p0 + p1) + (p2 + p3);
#pragma unroll
        for (int off = 1; off < 16; off <<= 1) rsum += __shfl_xor(rsum, off);
        l_i[i] += rsum;
        // pack 4 contiguous bf16 (k = llo*4..llo*4+3) -> one 8B LDS write
        u32x2 pk;
        pk[0] = (unsigned)f2bf(p0) | ((unsigned)f2bf(p1) << 16);
        pk[1] = (unsigned)f2bf(p2) | ((unsigned)f2bf(p3) << 16);
        *(u32x2*)&Ps[(w * 16 + lhi * 4 + i) * 72 + llo * 4] = pk;
      }

      // O += P V
      bf16x8 pa[2];
#pragma unroll
      for (int kk = 0; kk < 2; ++kk)
        pa[kk] = *(const bf16x8*)&Ps[(w * 16 + llo) * 72 + kk * 32 + lhi * 8];
      __builtin_amdgcn_s_setprio(1);
#pragma unroll
      for (int db = 0; db < 4; ++db)
#pragma unroll
        for (int kk = 0; kk < 2; ++kk) {
          bf16x8 bv = *(const bf16x8*)&Vs[buf][(db * 16 + llo) * 64 +
                                              ((kk * 32 + lhi * 8) ^ ((llo & 7) << 3))];
          o[db] = __builtin_amdgcn_mfma_f32_16x16x32_bf16(pa[kk], bv, o[db], 0, 0, 0);
        }
      __builtin_amdgcn_s_setprio(0);
    }
    blockbar();
    buf ^= 1;
  }

#pragma unroll
  for (int i = 0; i < 4; ++i) {
    float inv = 1.f / l_i[i];
    size_t row = tok0 + q0 + w * 16 + lhi * 4 + i;
#pragma unroll
    for (int db = 0; db < 4; ++db)
      y[row * CC_ + h * 64 + db * 16 + llo] = f2bf(o[db][i] * inv);
  }
}

extern "C" void kernel_launch(void* const* d_in, const int* in_sizes, int n_in,
                              void* d_out, int out_size, void* d_ws, size_t ws_size,
                              hipStream_t stream) {
  (void)in_sizes; (void)n_in; (void)out_size; (void)ws_size;
  const float* x      = (const float*)d_in[0];
  const float* ln1g   = (const float*)d_in[1];
  const float* ln1b   = (const float*)d_in[2];
  const float* W_attn = (const float*)d_in[3];
  const float* b_attn = (const float*)d_in[4];
  const float* W_ap   = (const float*)d_in[5];
  const float* b_ap   = (const float*)d_in[6];
  const float* ln2g   = (const float*)d_in[7];
  const float* ln2b   = (const float*)d_in[8];
  const float* W_fc   = (const float*)d_in[9];
  const float* b_fc   = (const float*)d_in[10];
  const float* W_mp   = (const float*)d_in[11];
  const float* b_mp   = (const float*)d_in[12];

  char* p = (char*)d_ws;
  u16* WTattn = (u16*)p; p += (size_t)3072 * 1024 * 2;
  u16* WTap   = (u16*)p; p += (size_t)1024 * 1024 * 2;
  u16* WTfc   = (u16*)p; p += (size_t)4096 * 1024 * 2;
  u16* WTmp   = (u16*)p; p += (size_t)4096 * 1024 * 2;
  u16* xn     = (u16*)p; p += (size_t)4096 * 1024 * 2;
  u16* qkvb   = (u16*)p; p += (size_t)4096 * 3072 * 2;
  u16* yb     = (u16*)p; p += (size_t)4096 * 1024 * 2;
  float* x1   = (float*)p; p += (size_t)4096 * 1024 * 4;
  u16* h2     = (u16*)p; p += (size_t)4096 * 1024 * 2;
  u16* fcb    = qkvb;            // fc activations alias qkv+yb (dead by then)
  u16* VT     = (u16*)x1;        // VT aliases x1 (x1 written after attn)
  float* mppart = (float*)d_ws;  // 16.78MB over WTattn+WTap+WTfc (dead at mp time)

  kconv_t<<<dim3(96, 32), 256, 0, stream>>>(W_attn, WTattn, 1024, 3072);
  kconv_t<<<dim3(32, 32), 256, 0, stream>>>(W_ap, WTap, 1024, 1024);
  kconv_t<<<dim3(128, 32), 256, 0, stream>>>(W_fc, WTfc, 1024, 4096);
  kconv_t<<<dim3(32, 128), 256, 0, stream>>>(W_mp, WTmp, 4096, 1024);

  kln<<<4096, 256, 0, stream>>>(x, ln1g, ln1b, xn);
  kgemm<0, 1><<<dim3(24, 32), 256, 0, stream>>>(xn, WTattn, b_attn, nullptr, qkvb, nullptr, 4096, 3072, 1024);
  kvtrans<<<dim3(32, 32), 256, 0, stream>>>(qkvb, VT);
  kattn<<<dim3(16, 2, 16), 512, 0, stream>>>(qkvb, VT, yb);
  kgemm<1, 1><<<dim3(8, 32), 256, 0, stream>>>(yb, WTap, b_ap, x, x1, nullptr, 4096, 1024, 1024);
  kln<<<4096, 256, 0, stream>>>(x1, ln2g, ln2b, h2);
  kgemm<2, 1><<<dim3(32, 32), 256, 0, stream>>>(h2, WTfc, b_fc, nullptr, fcb, nullptr, 4096, 4096, 1024);
  kgemm<1, 2><<<dim3(8, 32, 2), 256, 0, stream>>>(fcb, WTmp, b_mp, x1, (float*)d_out, mppart, 4096, 1024, 4096);
  kadd<<<4096, 256, 0, stream>>>((float*)d_out, mppart);
}